// Round 5
// baseline (296.664 us; speedup 1.0000x reference)
//
#include <hip/hip_runtime.h>
#include <stdint.h>

#define LOG2_HASHMAP_SIZE 19
#define HASHTABLE_SIZE (1u << LOG2_HASHMAP_SIZE)
#define HASHTABLE_MASK (HASHTABLE_SIZE - 1u)
#define RES_F 128.0f

typedef float f32x2 __attribute__((ext_vector_type(2)));
typedef float f32x4 __attribute__((ext_vector_type(4)));
typedef uint32_t u32x4 __attribute__((ext_vector_type(4)));

// Non-temporal load/store for STREAMING traffic (x, out): evict-first in L2
// so the 2 MiB bf16 hashtable stays L2-resident.
__device__ __forceinline__ f32x4 nt_load4(const f32x4* p) {
    return __builtin_nontemporal_load(p);
}
__device__ __forceinline__ void nt_store4(f32x4* p, f32x4 v) {
    __builtin_nontemporal_store(v, p);
}

__device__ __forceinline__ float bf16w_lo(uint32_t w) {
    return __uint_as_float(w << 16);
}
__device__ __forceinline__ float bf16w_hi(uint32_t w) {
    return __uint_as_float(w & 0xFFFF0000u);
}

// ---- Pass 1: convert fp32 table (float2/entry) -> bf16x2 (uint32/entry) ----
__device__ __forceinline__ uint32_t pack_bf16x2(float a, float b) {
    uint32_t ua = __float_as_uint(a);
    uint32_t ub = __float_as_uint(b);
    ua = ua + 0x7FFFu + ((ua >> 16) & 1u);   // RTNE
    ub = ub + 0x7FFFu + ((ub >> 16) & 1u);
    return (ua >> 16) | (ub & 0xFFFF0000u);
}

__global__ __launch_bounds__(256) void convert_table_kernel(
    const f32x4* __restrict__ table4,   // HASHTABLE_SIZE/2 float4 (2 entries each)
    u32x4* __restrict__ ws4)            // HASHTABLE_SIZE/4 uint4
{
    int i = blockIdx.x * blockDim.x + threadIdx.x;   // 1 uint4 = 4 entries
    f32x4 e01 = table4[2 * i + 0];
    f32x4 e23 = table4[2 * i + 1];
    u32x4 o;
    o.x = pack_bf16x2(e01.x, e01.y);
    o.y = pack_bf16x2(e01.z, e01.w);
    o.z = pack_bf16x2(e23.x, e23.y);
    o.w = pack_bf16x2(e23.z, e23.w);
    ws4[i] = o;
}

// ---- Pass 2: main kernel ----
// Hash = ix ^ iy*P1 ^ iz*P2; the two x-corners of a (y,z) pair differ by
// mm = fx^cx in {1,3,7,...}. One 16-B load at (i0 & ~3) covers BOTH corners
// when mm<=3 (75% of points); mm>3 adds one 4-B load per pair.
// Requests/point: 5 expected.
//
// VGPR discipline (R4 post-mortem): process the 4 points as 2 groups of 2 so
// peak live gather results are 8 x dwordx4 = 32 VGPRs, and force <=64 VGPRs
// via launch_bounds(256, 8) -> 8 waves/SIMD (occupancy halves past 64 VGPRs).
__global__ __launch_bounds__(256, 8) void featurefield_bf16_kernel(
    const f32x4* __restrict__ x4,       // N/4 * 3 float4
    const uint32_t* __restrict__ tb,    // HASHTABLE_SIZE bf16x2 entries
    f32x4* __restrict__ out4,           // N/4 * 2 float4
    int n_quads)
{
    int t = blockIdx.x * blockDim.x + threadIdx.x;
    if (t >= n_quads) return;

    const u32x4* tb4 = (const u32x4*)tb;

    f32x4 a = nt_load4(&x4[3 * t + 0]);
    f32x4 b = nt_load4(&x4[3 * t + 1]);
    f32x4 c = nt_load4(&x4[3 * t + 2]);

    float px[4] = {a.x, a.w, b.z, c.y};
    float py[4] = {a.y, b.x, b.w, c.z};
    float pz[4] = {a.z, b.y, c.x, c.w};

    f32x2 res[4];

    #pragma unroll
    for (int g = 0; g < 2; ++g) {
        uint32_t i0[2][4];   // fx-corner entry index per (point-in-group, yz-pair)
        uint32_t mm[2];
        float dxs[2], dys[2], dzs[2];

        #pragma unroll
        for (int kk = 0; kk < 2; ++kk) {
            int k = 2 * g + kk;
            float xs = px[k] * RES_F;
            float ys = py[k] * RES_F;
            float zs = pz[k] * RES_F;
            float fxf = floorf(xs), fyf = floorf(ys), fzf = floorf(zs);
            int fx = (int)fxf, fy = (int)fyf, fz = (int)fzf;
            int cx = (int)ceilf(xs), cy = (int)ceilf(ys), cz = (int)ceilf(zs);
            dxs[kk] = xs - fxf;
            dys[kk] = ys - fyf;
            dzs[kk] = zs - fzf;

            uint32_t ufx = (uint32_t)fx;
            mm[kk] = ufx ^ (uint32_t)cx;
            uint32_t fyp = (uint32_t)fy * 2654435761u;
            uint32_t cyp = (uint32_t)cy * 2654435761u;
            uint32_t fzp = (uint32_t)fz * 805459861u;
            uint32_t czp = (uint32_t)cz * 805459861u;

            i0[kk][0] = (ufx ^ fyp ^ fzp) & HASHTABLE_MASK;  // (fy,fz)
            i0[kk][1] = (ufx ^ cyp ^ fzp) & HASHTABLE_MASK;  // (cy,fz)
            i0[kk][2] = (ufx ^ fyp ^ czp) & HASHTABLE_MASK;  // (fy,cz)
            i0[kk][3] = (ufx ^ cyp ^ czp) & HASHTABLE_MASK;  // (cy,cz)
        }

        // 8 always-loads for this group, issued back-to-back.
        u32x4 q[2][4];
        #pragma unroll
        for (int kk = 0; kk < 2; ++kk) {
            #pragma unroll
            for (int j = 0; j < 4; ++j) {
                q[kk][j] = tb4[i0[kk][j] >> 2];
            }
        }

        // Extract corner words; far points (mm>3, ~25%) fetch the cx corner
        // with an extra 4-B load per pair.
        uint32_t w0[2][4], w1[2][4];
        #pragma unroll
        for (int kk = 0; kk < 2; ++kk) {
            #pragma unroll
            for (int j = 0; j < 4; ++j) {
                uint32_t e0 = i0[kk][j] & 3u;
                uint32_t e1 = (i0[kk][j] ^ mm[kk]) & 3u;
                uint32_t qq[4] = {q[kk][j].x, q[kk][j].y, q[kk][j].z, q[kk][j].w};
                w0[kk][j] = qq[e0];
                w1[kk][j] = qq[e1];
            }
            if (mm[kk] > 3u) {
                #pragma unroll
                for (int j = 0; j < 4; ++j) {
                    w1[kk][j] = tb[i0[kk][j] ^ mm[kk]];
                }
            }
        }

        // Trilinear interpolation for this group, reference ordering.
        #pragma unroll
        for (int kk = 0; kk < 2; ++kk) {
            float dx = dxs[kk], dy = dys[kk], dz = dzs[kk];
            float wx = 1.0f - dx, wy = 1.0f - dy, wz = 1.0f - dz;

            // pair j: 0=(fy,fz) 1=(cy,fz) 2=(fy,cz) 3=(cy,cz); w0=fx, w1=cx
            float c00x = bf16w_lo(w0[kk][0]) * wx + bf16w_lo(w1[kk][0]) * dx;
            float c00y = bf16w_hi(w0[kk][0]) * wx + bf16w_hi(w1[kk][0]) * dx;
            float c10x = bf16w_lo(w0[kk][1]) * wx + bf16w_lo(w1[kk][1]) * dx;
            float c10y = bf16w_hi(w0[kk][1]) * wx + bf16w_hi(w1[kk][1]) * dx;
            float c01x = bf16w_lo(w0[kk][2]) * wx + bf16w_lo(w1[kk][2]) * dx;
            float c01y = bf16w_hi(w0[kk][2]) * wx + bf16w_hi(w1[kk][2]) * dx;
            float c11x = bf16w_lo(w0[kk][3]) * wx + bf16w_lo(w1[kk][3]) * dx;
            float c11y = bf16w_hi(w0[kk][3]) * wx + bf16w_hi(w1[kk][3]) * dx;

            float c0x = c00x * wy + c10x * dy;
            float c0y = c00y * wy + c10y * dy;
            float c1x = c01x * wy + c11x * dy;
            float c1y = c01y * wy + c11y * dy;

            res[2 * g + kk].x = c0x * wz + c1x * dz;
            res[2 * g + kk].y = c0y * wz + c1y * dz;
        }
    }

    f32x4 o0 = {res[0].x, res[0].y, res[1].x, res[1].y};
    f32x4 o1 = {res[2].x, res[2].y, res[3].x, res[3].y};
    nt_store4(&out4[2 * t + 0], o0);
    nt_store4(&out4[2 * t + 1], o1);
}

// ---- Fallback (fp32 direct) if ws is too small ----
__global__ __launch_bounds__(256) void featurefield_fp32_kernel(
    const f32x4* __restrict__ x4,
    const float2* __restrict__ table,
    f32x4* __restrict__ out4,
    int n_quads)
{
    int t = blockIdx.x * blockDim.x + threadIdx.x;
    if (t >= n_quads) return;

    f32x4 a = nt_load4(&x4[3 * t + 0]);
    f32x4 b = nt_load4(&x4[3 * t + 1]);
    f32x4 c = nt_load4(&x4[3 * t + 2]);

    float px[4] = {a.x, a.w, b.z, c.y};
    float py[4] = {a.y, b.x, b.w, c.z};
    float pz[4] = {a.z, b.y, c.x, c.w};

    uint32_t h[4][8];
    float dxs[4], dys[4], dzs[4];

    #pragma unroll
    for (int k = 0; k < 4; ++k) {
        float xs = px[k] * RES_F, ys = py[k] * RES_F, zs = pz[k] * RES_F;
        float fxf = floorf(xs), fyf = floorf(ys), fzf = floorf(zs);
        int fx = (int)fxf, fy = (int)fyf, fz = (int)fzf;
        int cx = (int)ceilf(xs), cy = (int)ceilf(ys), cz = (int)ceilf(zs);
        dxs[k] = xs - fxf; dys[k] = ys - fyf; dzs[k] = zs - fzf;
        uint32_t ufx = (uint32_t)fx, ucx = (uint32_t)cx;
        uint32_t fyp = (uint32_t)fy * 2654435761u, cyp = (uint32_t)cy * 2654435761u;
        uint32_t fzp = (uint32_t)fz * 805459861u, czp = (uint32_t)cz * 805459861u;
        h[k][0] = (ufx ^ fyp ^ fzp) & HASHTABLE_MASK;
        h[k][1] = (ucx ^ fyp ^ fzp) & HASHTABLE_MASK;
        h[k][2] = (ufx ^ cyp ^ fzp) & HASHTABLE_MASK;
        h[k][3] = (ufx ^ fyp ^ czp) & HASHTABLE_MASK;
        h[k][4] = (ucx ^ cyp ^ fzp) & HASHTABLE_MASK;
        h[k][5] = (ucx ^ fyp ^ czp) & HASHTABLE_MASK;
        h[k][6] = (ufx ^ cyp ^ czp) & HASHTABLE_MASK;
        h[k][7] = (ucx ^ cyp ^ czp) & HASHTABLE_MASK;
    }

    float2 v[4][8];
    #pragma unroll
    for (int k = 0; k < 4; ++k)
        #pragma unroll
        for (int j = 0; j < 8; ++j)
            v[k][j] = table[h[k][j]];

    f32x2 res[4];
    #pragma unroll
    for (int k = 0; k < 4; ++k) {
        float dx = dxs[k], dy = dys[k], dz = dzs[k];
        float wx = 1.0f - dx, wy = 1.0f - dy, wz = 1.0f - dz;
        float c00x = v[k][0].x * wx + v[k][1].x * dx;
        float c00y = v[k][0].y * wx + v[k][1].y * dx;
        float c01x = v[k][3].x * wx + v[k][5].x * dx;
        float c01y = v[k][3].y * wx + v[k][5].y * dx;
        float c10x = v[k][2].x * wx + v[k][4].x * dx;
        float c10y = v[k][2].y * wx + v[k][4].y * dx;
        float c11x = v[k][6].x * wx + v[k][7].x * dx;
        float c11y = v[k][6].y * wx + v[k][7].y * dx;
        float c0x = c00x * wy + c10x * dy;
        float c0y = c00y * wy + c10y * dy;
        float c1x = c01x * wy + c11x * dy;
        float c1y = c01y * wy + c11y * dy;
        res[k].x = c0x * wz + c1x * dz;
        res[k].y = c0y * wz + c1y * dz;
    }

    f32x4 o0 = {res[0].x, res[0].y, res[1].x, res[1].y};
    f32x4 o1 = {res[2].x, res[2].y, res[3].x, res[3].y};
    nt_store4(&out4[2 * t + 0], o0);
    nt_store4(&out4[2 * t + 1], o1);
}

extern "C" void kernel_launch(void* const* d_in, const int* in_sizes, int n_in,
                              void* d_out, int out_size, void* d_ws, size_t ws_size,
                              hipStream_t stream) {
    const f32x4* x4 = (const f32x4*)d_in[0];
    f32x4* out4 = (f32x4*)d_out;

    int n_points = in_sizes[0] / 3;   // 4194304
    int n_quads = n_points / 4;       // 1048576
    int block = 256;
    int grid = (n_quads + block - 1) / block;  // 4096

    size_t need = (size_t)HASHTABLE_SIZE * 4u;   // 2 MiB bf16 table
    if (ws_size >= need) {
        const f32x4* table4 = (const f32x4*)d_in[1];
        u32x4* ws4 = (u32x4*)d_ws;
        int conv_threads = HASHTABLE_SIZE / 4;   // 131072
        convert_table_kernel<<<conv_threads / 256, 256, 0, stream>>>(table4, ws4);
        featurefield_bf16_kernel<<<grid, block, 0, stream>>>(
            x4, (const uint32_t*)d_ws, out4, n_quads);
    } else {
        const float2* table = (const float2*)d_in[1];
        featurefield_fp32_kernel<<<grid, block, 0, stream>>>(x4, table, out4, n_quads);
    }
}

// Round 6
// 178.362 us; speedup vs baseline: 1.6633x; 1.6633x over previous
//
#include <hip/hip_runtime.h>
#include <stdint.h>

#define LOG2_HASHMAP_SIZE 19
#define HASHTABLE_SIZE (1u << LOG2_HASHMAP_SIZE)
#define HASHTABLE_MASK (HASHTABLE_SIZE - 1u)
#define RES_F 128.0f

typedef float f32x2 __attribute__((ext_vector_type(2)));
typedef float f32x4 __attribute__((ext_vector_type(4)));
typedef uint32_t u32x4 __attribute__((ext_vector_type(4)));
typedef int i32x4 __attribute__((ext_vector_type(4)));

// Raw buffer loads: SRD base lives in SGPRs, so each gather costs ONE VGPR
// (the byte voffset) instead of a 64-bit address pair. This is what keeps
// the kernel under 64 VGPRs (R4: global-load addr pairs pushed it to 68;
// R5: forcing 64 anyway spilled -> 346 MB scratch writes).
__device__ u32x4 llvm_amdgcn_raw_buffer_load_v4u32(i32x4 rsrc, int voffset,
                                                   int soffset, int aux)
    __asm("llvm.amdgcn.raw.buffer.load.v4i32");
__device__ uint32_t llvm_amdgcn_raw_buffer_load_u32(i32x4 rsrc, int voffset,
                                                    int soffset, int aux)
    __asm("llvm.amdgcn.raw.buffer.load.i32");

__device__ __forceinline__ i32x4 make_srd(const void* p, uint32_t bytes) {
    union { const void* p; uint32_t u[2]; } a;
    a.p = p;
    i32x4 r;
    r.x = (int)a.u[0];                 // base[31:0]
    r.y = (int)(a.u[1] & 0xFFFFu);     // base[47:32], stride=0
    r.z = (int)bytes;                  // num_records (bytes, stride==0)
    r.w = 0x00020000;                  // raw untyped dword access
    return r;
}

// Non-temporal load/store for STREAMING traffic (x, out): evict-first in L2
// so the 2 MiB bf16 hashtable stays L2-resident.
__device__ __forceinline__ f32x2 nt_load2(const f32x2* p) {
    return __builtin_nontemporal_load(p);
}
__device__ __forceinline__ void nt_store4(f32x4* p, f32x4 v) {
    __builtin_nontemporal_store(v, p);
}

__device__ __forceinline__ float bf16w_lo(uint32_t w) {
    return __uint_as_float(w << 16);
}
__device__ __forceinline__ float bf16w_hi(uint32_t w) {
    return __uint_as_float(w & 0xFFFF0000u);
}

// Select one of 4 packed words by 2-bit index via explicit cndmask chain
// (dynamic local-array indexing risks scratch).
__device__ __forceinline__ uint32_t sel4(u32x4 q, uint32_t e) {
    uint32_t lo = (e & 1u) ? q.y : q.x;
    uint32_t hi = (e & 1u) ? q.w : q.z;
    return (e & 2u) ? hi : lo;
}

// ---- Pass 1: convert fp32 table (float2/entry) -> bf16x2 (uint32/entry) ----
__device__ __forceinline__ uint32_t pack_bf16x2(float a, float b) {
    uint32_t ua = __float_as_uint(a);
    uint32_t ub = __float_as_uint(b);
    ua = ua + 0x7FFFu + ((ua >> 16) & 1u);   // RTNE
    ub = ub + 0x7FFFu + ((ub >> 16) & 1u);
    return (ua >> 16) | (ub & 0xFFFF0000u);
}

__global__ __launch_bounds__(256) void convert_table_kernel(
    const f32x4* __restrict__ table4,   // HASHTABLE_SIZE/2 float4 (2 entries each)
    u32x4* __restrict__ ws4)            // HASHTABLE_SIZE/4 uint4
{
    int i = blockIdx.x * blockDim.x + threadIdx.x;   // 1 uint4 = 4 entries
    f32x4 e01 = table4[2 * i + 0];
    f32x4 e23 = table4[2 * i + 1];
    u32x4 o;
    o.x = pack_bf16x2(e01.x, e01.y);
    o.y = pack_bf16x2(e01.z, e01.w);
    o.z = pack_bf16x2(e23.x, e23.y);
    o.w = pack_bf16x2(e23.z, e23.w);
    ws4[i] = o;
}

// ---- Pass 2: main kernel, 2 points per thread ----
// Hash = ix ^ iy*P1 ^ iz*P2; the two x-corners of a (y,z) pair differ by
// mm = fx^cx in {1,3,7,...}. One 16-B load at entry (i0 & ~3) covers BOTH
// corners when mm<=3 (75% of points); mm>3 adds one 4-B load per pair.
// 2 pts/thread keeps peak live state ~58 VGPRs -> 8 waves/SIMD for real.
__global__ __launch_bounds__(256, 8) void featurefield_bf16_kernel(
    const f32x2* __restrict__ x2,       // N/2 * 3 float2
    const uint32_t* __restrict__ tb,    // HASHTABLE_SIZE bf16x2 entries
    f32x4* __restrict__ out4,           // N/2 float4 (2 pts * 2 feats)
    int n_pairs)
{
    int t = blockIdx.x * blockDim.x + threadIdx.x;
    if (t >= n_pairs) return;

    i32x4 srd = make_srd(tb, HASHTABLE_SIZE * 4u);

    f32x2 A = nt_load2(&x2[3 * t + 0]);   // p0.x p0.y
    f32x2 B = nt_load2(&x2[3 * t + 1]);   // p0.z p1.x
    f32x2 C = nt_load2(&x2[3 * t + 2]);   // p1.y p1.z

    float px[2] = {A.x, B.y};
    float py[2] = {A.y, C.x};
    float pz[2] = {B.x, C.y};

    uint32_t i0[2][4];
    uint32_t mm[2];
    float dxs[2], dys[2], dzs[2];

    #pragma unroll
    for (int k = 0; k < 2; ++k) {
        float xs = px[k] * RES_F;
        float ys = py[k] * RES_F;
        float zs = pz[k] * RES_F;
        float fxf = floorf(xs), fyf = floorf(ys), fzf = floorf(zs);
        int fx = (int)fxf, fy = (int)fyf, fz = (int)fzf;
        int cx = (int)ceilf(xs), cy = (int)ceilf(ys), cz = (int)ceilf(zs);
        dxs[k] = xs - fxf;
        dys[k] = ys - fyf;
        dzs[k] = zs - fzf;

        uint32_t ufx = (uint32_t)fx;
        mm[k] = ufx ^ (uint32_t)cx;
        uint32_t fyp = (uint32_t)fy * 2654435761u;
        uint32_t cyp = (uint32_t)cy * 2654435761u;
        uint32_t fzp = (uint32_t)fz * 805459861u;
        uint32_t czp = (uint32_t)cz * 805459861u;

        i0[k][0] = (ufx ^ fyp ^ fzp) & HASHTABLE_MASK;  // (fy,fz)
        i0[k][1] = (ufx ^ cyp ^ fzp) & HASHTABLE_MASK;  // (cy,fz)
        i0[k][2] = (ufx ^ fyp ^ czp) & HASHTABLE_MASK;  // (fy,cz)
        i0[k][3] = (ufx ^ cyp ^ czp) & HASHTABLE_MASK;  // (cy,cz)
    }

    // 8 always-loads (16 B each), issued back-to-back; voffset = entry*4 & ~15.
    u32x4 q[2][4];
    #pragma unroll
    for (int k = 0; k < 2; ++k) {
        #pragma unroll
        for (int j = 0; j < 4; ++j) {
            q[k][j] = llvm_amdgcn_raw_buffer_load_v4u32(
                srd, (int)((i0[k][j] << 2) & ~15u), 0, 0);
        }
    }

    // Extract both corners; far points (mm>3, ~25%) fetch cx corner with an
    // extra 4-B load per pair.
    uint32_t w0[2][4], w1[2][4];
    #pragma unroll
    for (int k = 0; k < 2; ++k) {
        #pragma unroll
        for (int j = 0; j < 4; ++j) {
            uint32_t e0 = i0[k][j] & 3u;
            w0[k][j] = sel4(q[k][j], e0);
            w1[k][j] = sel4(q[k][j], e0 ^ (mm[k] & 3u));
        }
        if (mm[k] > 3u) {
            #pragma unroll
            for (int j = 0; j < 4; ++j) {
                w1[k][j] = llvm_amdgcn_raw_buffer_load_u32(
                    srd, (int)((i0[k][j] ^ mm[k]) << 2), 0, 0);
            }
        }
    }

    // Trilinear interpolation, reference ordering.
    f32x2 res[2];
    #pragma unroll
    for (int k = 0; k < 2; ++k) {
        float dx = dxs[k], dy = dys[k], dz = dzs[k];
        float wx = 1.0f - dx, wy = 1.0f - dy, wz = 1.0f - dz;

        // pair j: 0=(fy,fz) 1=(cy,fz) 2=(fy,cz) 3=(cy,cz); w0=fx, w1=cx
        float c00x = bf16w_lo(w0[k][0]) * wx + bf16w_lo(w1[k][0]) * dx;
        float c00y = bf16w_hi(w0[k][0]) * wx + bf16w_hi(w1[k][0]) * dx;
        float c10x = bf16w_lo(w0[k][1]) * wx + bf16w_lo(w1[k][1]) * dx;
        float c10y = bf16w_hi(w0[k][1]) * wx + bf16w_hi(w1[k][1]) * dx;
        float c01x = bf16w_lo(w0[k][2]) * wx + bf16w_lo(w1[k][2]) * dx;
        float c01y = bf16w_hi(w0[k][2]) * wx + bf16w_hi(w1[k][2]) * dx;
        float c11x = bf16w_lo(w0[k][3]) * wx + bf16w_lo(w1[k][3]) * dx;
        float c11y = bf16w_hi(w0[k][3]) * wx + bf16w_hi(w1[k][3]) * dx;

        float c0x = c00x * wy + c10x * dy;
        float c0y = c00y * wy + c10y * dy;
        float c1x = c01x * wy + c11x * dy;
        float c1y = c01y * wy + c11y * dy;

        res[k].x = c0x * wz + c1x * dz;
        res[k].y = c0y * wz + c1y * dz;
    }

    f32x4 o = {res[0].x, res[0].y, res[1].x, res[1].y};
    nt_store4(&out4[t], o);
}

// ---- Fallback (fp32 direct) if ws is too small ----
__global__ __launch_bounds__(256) void featurefield_fp32_kernel(
    const f32x2* __restrict__ x2,
    const float2* __restrict__ table,
    f32x4* __restrict__ out4,
    int n_pairs)
{
    int t = blockIdx.x * blockDim.x + threadIdx.x;
    if (t >= n_pairs) return;

    f32x2 A = nt_load2(&x2[3 * t + 0]);
    f32x2 B = nt_load2(&x2[3 * t + 1]);
    f32x2 C = nt_load2(&x2[3 * t + 2]);

    float px[2] = {A.x, B.y};
    float py[2] = {A.y, C.x};
    float pz[2] = {B.x, C.y};

    f32x2 res[2];
    #pragma unroll
    for (int k = 0; k < 2; ++k) {
        float xs = px[k] * RES_F, ys = py[k] * RES_F, zs = pz[k] * RES_F;
        float fxf = floorf(xs), fyf = floorf(ys), fzf = floorf(zs);
        int fx = (int)fxf, fy = (int)fyf, fz = (int)fzf;
        int cx = (int)ceilf(xs), cy = (int)ceilf(ys), cz = (int)ceilf(zs);
        float dx = xs - fxf, dy = ys - fyf, dz = zs - fzf;
        uint32_t ufx = (uint32_t)fx, ucx = (uint32_t)cx;
        uint32_t fyp = (uint32_t)fy * 2654435761u, cyp = (uint32_t)cy * 2654435761u;
        uint32_t fzp = (uint32_t)fz * 805459861u, czp = (uint32_t)cz * 805459861u;
        uint32_t h0 = (ufx ^ fyp ^ fzp) & HASHTABLE_MASK;
        uint32_t h1 = (ucx ^ fyp ^ fzp) & HASHTABLE_MASK;
        uint32_t h2 = (ufx ^ cyp ^ fzp) & HASHTABLE_MASK;
        uint32_t h3 = (ufx ^ fyp ^ czp) & HASHTABLE_MASK;
        uint32_t h4 = (ucx ^ cyp ^ fzp) & HASHTABLE_MASK;
        uint32_t h5 = (ucx ^ fyp ^ czp) & HASHTABLE_MASK;
        uint32_t h6 = (ufx ^ cyp ^ czp) & HASHTABLE_MASK;
        uint32_t h7 = (ucx ^ cyp ^ czp) & HASHTABLE_MASK;

        float2 v0 = table[h0], v1 = table[h1], v2 = table[h2], v3 = table[h3];
        float2 v4 = table[h4], v5 = table[h5], v6 = table[h6], v7 = table[h7];

        float wx = 1.0f - dx, wy = 1.0f - dy, wz = 1.0f - dz;
        float c00x = v0.x * wx + v1.x * dx, c00y = v0.y * wx + v1.y * dx;
        float c01x = v3.x * wx + v5.x * dx, c01y = v3.y * wx + v5.y * dx;
        float c10x = v2.x * wx + v4.x * dx, c10y = v2.y * wx + v4.y * dx;
        float c11x = v6.x * wx + v7.x * dx, c11y = v6.y * wx + v7.y * dx;
        float c0x = c00x * wy + c10x * dy, c0y = c00y * wy + c10y * dy;
        float c1x = c01x * wy + c11x * dy, c1y = c01y * wy + c11y * dy;
        res[k].x = c0x * wz + c1x * dz;
        res[k].y = c0y * wz + c1y * dz;
    }

    f32x4 o = {res[0].x, res[0].y, res[1].x, res[1].y};
    nt_store4(&out4[t], o);
}

extern "C" void kernel_launch(void* const* d_in, const int* in_sizes, int n_in,
                              void* d_out, int out_size, void* d_ws, size_t ws_size,
                              hipStream_t stream) {
    const f32x2* x2 = (const f32x2*)d_in[0];
    f32x4* out4 = (f32x4*)d_out;

    int n_points = in_sizes[0] / 3;   // 4194304
    int n_pairs = n_points / 2;       // 2097152
    int block = 256;
    int grid = (n_pairs + block - 1) / block;  // 8192

    size_t need = (size_t)HASHTABLE_SIZE * 4u;   // 2 MiB bf16 table
    if (ws_size >= need) {
        const f32x4* table4 = (const f32x4*)d_in[1];
        u32x4* ws4 = (u32x4*)d_ws;
        int conv_threads = HASHTABLE_SIZE / 4;   // 131072
        convert_table_kernel<<<conv_threads / 256, 256, 0, stream>>>(table4, ws4);
        featurefield_bf16_kernel<<<grid, block, 0, stream>>>(
            x2, (const uint32_t*)d_ws, out4, n_pairs);
    } else {
        const float2* table = (const float2*)d_in[1];
        featurefield_fp32_kernel<<<grid, block, 0, stream>>>(x2, table, out4, n_pairs);
    }
}